// Round 8
// baseline (847.031 us; speedup 1.0000x reference)
//
#include <hip/hip_runtime.h>
#include <hip/hip_bf16.h>
#include <math.h>

typedef __bf16 bf16x8 __attribute__((ext_vector_type(8)));
typedef float  f32x4  __attribute__((ext_vector_type(4)));
typedef unsigned short ushort_t;

#define LDK 72   // padded LDS row (bf16): 144B stride

// ws layout (bytes):
//   Kg : [12][4096][64] bf16 (gathered, row-major)            @ 0
//   Vq : [12][64 kt][64 d][64 s] bf16 (gathered, key-permuted)@ 6291456
//   l_acc: [4096*12] f32                                      @ 12582912
#define KG_OFF  0
#define VQ_OFF  6291456
#define LACC_OFF 12582912

__device__ __forceinline__ int gather_pos(int gi, int group) {
    const int lsl = 10 + group;
    const int seg = gi >> lsl;
    const int j   = gi - (seg << lsl);
    return (seg << lsl) + group + ((j & 1023) << group);
}

// key permutation for PV B-frag: stored index s -> original key-in-tile
__device__ __forceinline__ int perm_key(int s) {
    const int kp2 = s >> 5, s5 = s & 31;
    const int quad = s5 >> 3, rem = s5 & 7;
    return kp2 * 32 + (rem >> 2) * 16 + quad * 4 + (rem & 3);
}

// ---- preconvert: Kg row-major bf16; Vq key-permuted [kt][d][s] ----
__global__ __launch_bounds__(256)
void preconvert_kernel(const float* __restrict__ K, const float* __restrict__ V,
                       ushort_t* __restrict__ Kg, ushort_t* __restrict__ Vq)
{
    const int HD = 768;
    int b = blockIdx.x;
    const int tid = threadIdx.x;
    if (b < 768) {
        const int h = b % 12, gi0 = (b / 12) * 64;
        const int group = h >> 2;
        const int gi = gi0 + (tid >> 2);
        const int d0 = (tid & 3) << 4;
        const int pos = gather_pos(gi, group);
        const float* kp = K + (size_t)pos * HD + h * 64 + d0;
        float4 x0 = ((const float4*)kp)[0], x1 = ((const float4*)kp)[1];
        float4 x2 = ((const float4*)kp)[2], x3 = ((const float4*)kp)[3];
        bf16x8 w0, w1;
        w0[0]=(__bf16)x0.x; w0[1]=(__bf16)x0.y; w0[2]=(__bf16)x0.z; w0[3]=(__bf16)x0.w;
        w0[4]=(__bf16)x1.x; w0[5]=(__bf16)x1.y; w0[6]=(__bf16)x1.z; w0[7]=(__bf16)x1.w;
        w1[0]=(__bf16)x2.x; w1[1]=(__bf16)x2.y; w1[2]=(__bf16)x2.z; w1[3]=(__bf16)x2.w;
        w1[4]=(__bf16)x3.x; w1[5]=(__bf16)x3.y; w1[6]=(__bf16)x3.z; w1[7]=(__bf16)x3.w;
        ushort_t* out = Kg + ((size_t)(h * 4096 + gi)) * 64 + d0;
        *(bf16x8*)out = w0;
        *(bf16x8*)(out + 8) = w1;
    } else {
        // V: stage 64key x 64d tile in LDS, emit permuted [d][s]
        b -= 768;
        const int h = b % 12, kt = b / 12;        // global k-tile 0..63
        const int group = h >> 2;
        __shared__ __align__(16) __bf16 Ts[64 * LDK];
        const int gil = tid >> 2;
        const int d0 = (tid & 3) << 4;
        const int pos = gather_pos(kt * 64 + gil, group);
        const float* vpp = V + (size_t)pos * HD + h * 64 + d0;
        float4 x0 = ((const float4*)vpp)[0], x1 = ((const float4*)vpp)[1];
        float4 x2 = ((const float4*)vpp)[2], x3 = ((const float4*)vpp)[3];
        bf16x8 w0, w1;
        w0[0]=(__bf16)x0.x; w0[1]=(__bf16)x0.y; w0[2]=(__bf16)x0.z; w0[3]=(__bf16)x0.w;
        w0[4]=(__bf16)x1.x; w0[5]=(__bf16)x1.y; w0[6]=(__bf16)x1.z; w0[7]=(__bf16)x1.w;
        w1[0]=(__bf16)x2.x; w1[1]=(__bf16)x2.y; w1[2]=(__bf16)x2.z; w1[3]=(__bf16)x2.w;
        w1[4]=(__bf16)x3.x; w1[5]=(__bf16)x3.y; w1[6]=(__bf16)x3.z; w1[7]=(__bf16)x3.w;
        *(bf16x8*)&Ts[gil * LDK + d0]     = w0;
        *(bf16x8*)&Ts[gil * LDK + d0 + 8] = w1;
        __syncthreads();
        // emit: thread -> d = tid>>2, s0 = (tid&3)*16, 16 entries = 2 b128
        const int d = tid >> 2;
        const int s0 = (tid & 3) << 4;
        bf16x8 o0, o1;
        #pragma unroll
        for (int i = 0; i < 8; ++i) {
            o0[i] = Ts[perm_key(s0 + i) * LDK + d];
            o1[i] = Ts[perm_key(s0 + 8 + i) * LDK + d];
        }
        ushort_t* out = Vq + (((size_t)(h * 64 + kt)) * 64 + d) * 64 + s0;
        *(bf16x8*)out = o0;
        *(bf16x8*)(out + 8) = o1;
    }
}

// ---- attention: LDS-staged K/V, transpose trick (no P round-trip), 2-deep prefetch ----
__global__ __launch_bounds__(256)
void dilated_attn_kernel(const float* __restrict__ Q,
                         const ushort_t* __restrict__ Kg,
                         const ushort_t* __restrict__ Vq,
                         const int* __restrict__ is_causal_p,
                         float* __restrict__ Out,
                         float* __restrict__ l_acc)
{
    const int HD = 768;
    const int bx  = blockIdx.x;              // 0..3071, LPT: heavy q-tiles first
    const int qt  = 63 - (bx / 48);
    const int rem = bx % 48;
    const int h   = rem % 12;
    const int c   = rem / 12;                // chunk 0..3 (16 k-tiles each)
    const int group = h >> 2;
    const int sl    = 1024 << group;
    const int causal = (*is_causal_p) != 0;

    const int q0 = qt << 6;
    const int qb = q0 & (sl - 1);
    const int seg_start = q0 - qb;
    const int diag_kt = qb >> 6;
    const int nkt = causal ? (diag_kt + 1) : (sl >> 6);
    const int kt0 = c << 4;
    if (kt0 >= nkt) return;
    const int kend = min(kt0 + 16, nkt);
    const int nch  = (nkt + 15) >> 4;

    const int tid  = threadIdx.x;
    const int wave = tid >> 6;
    const int lane = tid & 63;
    const int l15  = lane & 15;
    const int quad = lane >> 4;

    __shared__ __align__(16) __bf16 Ks[2][64 * LDK];   // [key][d]
    __shared__ __align__(16) __bf16 Vs[2][64 * LDK];   // [d][s] (key-permuted)

    const int srow = tid >> 3;               // 0..31
    const int scol = (tid & 7) << 3;         // 0..56
    const ushort_t* kg_head = Kg + (size_t)h * 4096 * 64;
    const ushort_t* vq_head = Vq + (size_t)h * 64 * 4096;

    // ---- Q B-frags (B[k=d][n=q]: n=l15, k=quad*8+j), scale = 0.125*log2(e) ----
    bf16x8 bq0, bq1;
    {
        const float s = 0.125f * 1.4426950408889634f;
        const int qrow = q0 + wave * 16 + l15;
        const float* qptr = Q + (size_t)qrow * HD + h * 64;
        float4 x0 = ((const float4*)(qptr + quad * 8))[0];
        float4 x1 = ((const float4*)(qptr + quad * 8))[1];
        float4 y0 = ((const float4*)(qptr + 32 + quad * 8))[0];
        float4 y1 = ((const float4*)(qptr + 32 + quad * 8))[1];
        bq0[0]=(__bf16)(x0.x*s); bq0[1]=(__bf16)(x0.y*s); bq0[2]=(__bf16)(x0.z*s); bq0[3]=(__bf16)(x0.w*s);
        bq0[4]=(__bf16)(x1.x*s); bq0[5]=(__bf16)(x1.y*s); bq0[6]=(__bf16)(x1.z*s); bq0[7]=(__bf16)(x1.w*s);
        bq1[0]=(__bf16)(y0.x*s); bq1[1]=(__bf16)(y0.y*s); bq1[2]=(__bf16)(y0.z*s); bq1[3]=(__bf16)(y0.w*s);
        bq1[4]=(__bf16)(y1.x*s); bq1[5]=(__bf16)(y1.y*s); bq1[6]=(__bf16)(y1.z*s); bq1[7]=(__bf16)(y1.w*s);
    }

    f32x4 o[4];
    #pragma unroll
    for (int t = 0; t < 4; ++t) o[t] = (f32x4){0.f, 0.f, 0.f, 0.f};
    float l_r = 0.f;
    const int q_in_seg = qb + wave * 16 + l15;

    // 2-deep register prefetch pipeline
    bf16x8 rK[2][2], rV[2][2];
    auto load_tile = [&](int kt, int s) {
        const ushort_t* kb = kg_head + (size_t)(seg_start + (kt << 6)) * 64;
        rK[s][0] = *(const bf16x8*)(kb + srow * 64 + scol);
        rK[s][1] = *(const bf16x8*)(kb + (srow + 32) * 64 + scol);
        const ushort_t* vb = vq_head + (size_t)((seg_start >> 6) + kt) * 4096;
        rV[s][0] = *(const bf16x8*)(vb + srow * 64 + scol);
        rV[s][1] = *(const bf16x8*)(vb + (srow + 32) * 64 + scol);
    };
    auto store_tile = [&](int s, int buf) {
        *(bf16x8*)&Ks[buf][srow * LDK + scol]        = rK[s][0];
        *(bf16x8*)&Ks[buf][(srow + 32) * LDK + scol] = rK[s][1];
        *(bf16x8*)&Vs[buf][srow * LDK + scol]        = rV[s][0];
        *(bf16x8*)&Vs[buf][(srow + 32) * LDK + scol] = rV[s][1];
    };

    load_tile(kt0, 0);
    store_tile(0, 0);
    if (kt0 + 1 < kend) load_tile(kt0 + 1, 1);
    __syncthreads();

    for (int kt = kt0; kt < kend; ++kt) {
        const int cur = (kt - kt0) & 1;
        if (kt + 2 < kend) load_tile(kt + 2, cur);   // set `cur` already drained to LDS

        // ---- S^T = K * Q^T : A = K-frag from LDS (m=key), B = Q-frag ----
        f32x4 sacc[4];
        #pragma unroll
        for (int kg = 0; kg < 4; ++kg) {
            bf16x8 ka0 = *(const bf16x8*)&Ks[cur][(kg * 16 + l15) * LDK + quad * 8];
            bf16x8 ka1 = *(const bf16x8*)&Ks[cur][(kg * 16 + l15) * LDK + 32 + quad * 8];
            f32x4 cc = (f32x4){0.f, 0.f, 0.f, 0.f};
            cc = __builtin_amdgcn_mfma_f32_16x16x32_bf16(ka0, bq0, cc, 0, 0, 0);
            cc = __builtin_amdgcn_mfma_f32_16x16x32_bf16(ka1, bq1, cc, 0, 0, 0);
            sacc[kg] = cc;
        }

        // ---- P^T = 2^(S^T) in registers; pack straight into PV B-frags ----
        const bool maskT = causal && (kt == diag_kt);
        bf16x8 pb[2];
        #pragma unroll
        for (int kg = 0; kg < 4; ++kg) {
            #pragma unroll
            for (int r = 0; r < 4; ++r) {
                const int key = (kt << 6) + kg * 16 + quad * 4 + r;
                float p = __builtin_amdgcn_exp2f(sacc[kg][r]);
                if (maskT && key > q_in_seg) p = 0.f;
                l_r += p;
                pb[kg >> 1][(kg & 1) * 4 + r] = (__bf16)p;
            }
        }

        // ---- O^T += V^T * P^T : A = permuted V-frag from LDS (b128), B = pb ----
        #pragma unroll
        for (int kp2 = 0; kp2 < 2; ++kp2) {
            #pragma unroll
            for (int t = 0; t < 4; ++t) {
                bf16x8 va = *(const bf16x8*)&Vs[cur][(t * 16 + l15) * LDK + kp2 * 32 + quad * 8];
                o[t] = __builtin_amdgcn_mfma_f32_16x16x32_bf16(va, pb[kp2], o[t], 0, 0, 0);
            }
        }

        if (kt + 1 < kend) store_tile(cur ^ 1, cur ^ 1);
        __syncthreads();
    }

    // ---- epilogue: l held per (q=l15, quad) -> reduce across quads only ----
    l_r += __shfl_xor(l_r, 16, 64);
    l_r += __shfl_xor(l_r, 32, 64);
    const int row = q0 + wave * 16 + l15;
    if (nch == 1) {
        const float inv = 1.0f / l_r;
        #pragma unroll
        for (int t = 0; t < 4; ++t) {
            f32x4 v = o[t];
            float4 w = {v[0] * inv, v[1] * inv, v[2] * inv, v[3] * inv};
            *(float4*)(Out + (size_t)row * HD + h * 64 + t * 16 + quad * 4) = w;
        }
    } else {
        if (lane < 16) atomicAdd(&l_acc[row * 12 + h], l_r);
        #pragma unroll
        for (int t = 0; t < 4; ++t)
            #pragma unroll
            for (int r = 0; r < 4; ++r)
                atomicAdd(&Out[(size_t)row * HD + h * 64 + t * 16 + quad * 4 + r], o[t][r]);
    }
}

// ---- finalize: divide multi-chunk rows (nkt > 16) by accumulated l ----
__global__ __launch_bounds__(256)
void finalize_kernel(float* __restrict__ Out, const float* __restrict__ l_acc,
                     const int* __restrict__ is_causal_p)
{
    const int causal = (*is_causal_p) != 0;
    const int idx = blockIdx.x * 256 + threadIdx.x;
    const int rh = idx >> 4;
    const int d4 = idx & 15;
    const int h = rh % 12;
    const int row = rh / 12;
    const int group = h >> 2;
    const int sl = 1024 << group;
    const int q0 = row & ~63;
    const int qb = q0 & (sl - 1);
    const int nkt = causal ? ((qb >> 6) + 1) : (sl >> 6);
    if (nkt <= 16) return;
    const float inv = 1.0f / l_acc[rh];
    float4* p = (float4*)Out + (size_t)rh * 16 + d4;
    float4 v = *p;
    v.x *= inv; v.y *= inv; v.z *= inv; v.w *= inv;
    *p = v;
}

extern "C" void kernel_launch(void* const* d_in, const int* in_sizes, int n_in,
                              void* d_out, int out_size, void* d_ws, size_t ws_size,
                              hipStream_t stream) {
    (void)in_sizes; (void)n_in; (void)out_size; (void)ws_size;
    const float* Q = (const float*)d_in[0];
    const float* K = (const float*)d_in[1];
    const float* V = (const float*)d_in[2];
    const int* isc = (const int*)d_in[3];
    float* Out = (float*)d_out;
    ushort_t* Kg   = (ushort_t*)((char*)d_ws + KG_OFF);
    ushort_t* Vq   = (ushort_t*)((char*)d_ws + VQ_OFF);
    float*    lacc = (float*)((char*)d_ws + LACC_OFF);

    hipMemsetAsync(Out, 0, (size_t)4096 * 12 * 64 * 4, stream);
    hipMemsetAsync(lacc, 0, (size_t)4096 * 12 * 4, stream);
    preconvert_kernel<<<1536, 256, 0, stream>>>(K, V, Kg, Vq);
    dilated_attn_kernel<<<3072, 256, 0, stream>>>(Q, Kg, Vq, isc, Out, lacc);
    finalize_kernel<<<3072, 256, 0, stream>>>(Out, lacc, isc);
}

// Round 9
// 159.287 us; speedup vs baseline: 5.3176x; 5.3176x over previous
//
#include <hip/hip_runtime.h>
#include <hip/hip_bf16.h>
#include <math.h>

typedef __bf16 bf16x8 __attribute__((ext_vector_type(8)));
typedef float  f32x4  __attribute__((ext_vector_type(4)));
typedef unsigned short ushort_t;

#define LDK 72   // padded LDS row (bf16): 144B stride

// ws layout (bytes):
//   Kg : [12][4096][64] bf16 (gathered, row-major)            @ 0
//   Vq : [12][64 kt][64 d][64 s] bf16 (gathered, key-permuted)@ 6291456
//   l_acc: [4096*12] f32                                      @ 12582912
#define KG_OFF  0
#define VQ_OFF  6291456
#define LACC_OFF 12582912

__device__ __forceinline__ int gather_pos(int gi, int group) {
    const int lsl = 10 + group;
    const int seg = gi >> lsl;
    const int j   = gi - (seg << lsl);
    return (seg << lsl) + group + ((j & 1023) << group);
}

// key permutation for PV B-frag: stored index s -> original key-in-tile
__device__ __forceinline__ int perm_key(int s) {
    const int kp2 = s >> 5, s5 = s & 31;
    const int quad = s5 >> 3, rem = s5 & 7;
    return kp2 * 32 + (rem >> 2) * 16 + quad * 4 + (rem & 3);
}

// ---- preconvert: Kg row-major bf16; Vq key-permuted [kt][d][s] ----
__global__ __launch_bounds__(256)
void preconvert_kernel(const float* __restrict__ K, const float* __restrict__ V,
                       ushort_t* __restrict__ Kg, ushort_t* __restrict__ Vq)
{
    const int HD = 768;
    int b = blockIdx.x;
    const int tid = threadIdx.x;
    if (b < 768) {
        const int h = b % 12, gi0 = (b / 12) * 64;
        const int group = h >> 2;
        const int gi = gi0 + (tid >> 2);
        const int d0 = (tid & 3) << 4;
        const int pos = gather_pos(gi, group);
        const float* kp = K + (size_t)pos * HD + h * 64 + d0;
        float4 x0 = ((const float4*)kp)[0], x1 = ((const float4*)kp)[1];
        float4 x2 = ((const float4*)kp)[2], x3 = ((const float4*)kp)[3];
        bf16x8 w0, w1;
        w0[0]=(__bf16)x0.x; w0[1]=(__bf16)x0.y; w0[2]=(__bf16)x0.z; w0[3]=(__bf16)x0.w;
        w0[4]=(__bf16)x1.x; w0[5]=(__bf16)x1.y; w0[6]=(__bf16)x1.z; w0[7]=(__bf16)x1.w;
        w1[0]=(__bf16)x2.x; w1[1]=(__bf16)x2.y; w1[2]=(__bf16)x2.z; w1[3]=(__bf16)x2.w;
        w1[4]=(__bf16)x3.x; w1[5]=(__bf16)x3.y; w1[6]=(__bf16)x3.z; w1[7]=(__bf16)x3.w;
        ushort_t* out = Kg + ((size_t)(h * 4096 + gi)) * 64 + d0;
        *(bf16x8*)out = w0;
        *(bf16x8*)(out + 8) = w1;
    } else {
        // V: stage 64key x 64d tile in LDS, emit permuted [d][s]
        b -= 768;
        const int h = b % 12, kt = b / 12;        // global k-tile 0..63
        const int group = h >> 2;
        __shared__ __align__(16) __bf16 Ts[64 * LDK];
        const int gil = tid >> 2;
        const int d0 = (tid & 3) << 4;
        const int pos = gather_pos(kt * 64 + gil, group);
        const float* vpp = V + (size_t)pos * HD + h * 64 + d0;
        float4 x0 = ((const float4*)vpp)[0], x1 = ((const float4*)vpp)[1];
        float4 x2 = ((const float4*)vpp)[2], x3 = ((const float4*)vpp)[3];
        bf16x8 w0, w1;
        w0[0]=(__bf16)x0.x; w0[1]=(__bf16)x0.y; w0[2]=(__bf16)x0.z; w0[3]=(__bf16)x0.w;
        w0[4]=(__bf16)x1.x; w0[5]=(__bf16)x1.y; w0[6]=(__bf16)x1.z; w0[7]=(__bf16)x1.w;
        w1[0]=(__bf16)x2.x; w1[1]=(__bf16)x2.y; w1[2]=(__bf16)x2.z; w1[3]=(__bf16)x2.w;
        w1[4]=(__bf16)x3.x; w1[5]=(__bf16)x3.y; w1[6]=(__bf16)x3.z; w1[7]=(__bf16)x3.w;
        *(bf16x8*)&Ts[gil * LDK + d0]     = w0;
        *(bf16x8*)&Ts[gil * LDK + d0 + 8] = w1;
        __syncthreads();
        // emit: thread -> d = tid>>2, s0 = (tid&3)*16, 16 entries = 2 b128
        const int d = tid >> 2;
        const int s0 = (tid & 3) << 4;
        bf16x8 o0, o1;
        #pragma unroll
        for (int i = 0; i < 8; ++i) {
            o0[i] = Ts[perm_key(s0 + i) * LDK + d];
            o1[i] = Ts[perm_key(s0 + 8 + i) * LDK + d];
        }
        ushort_t* out = Vq + (((size_t)(h * 64 + kt)) * 64 + d) * 64 + s0;
        *(bf16x8*)out = o0;
        *(bf16x8*)(out + 8) = o1;
    }
}

// ---- attention: LDS-staged K/V, transpose trick, 1-deep SCALAR-register prefetch ----
__global__ __launch_bounds__(256)
void dilated_attn_kernel(const float* __restrict__ Q,
                         const ushort_t* __restrict__ Kg,
                         const ushort_t* __restrict__ Vq,
                         const int* __restrict__ is_causal_p,
                         float* __restrict__ Out,
                         float* __restrict__ l_acc)
{
    const int HD = 768;
    const int bx  = blockIdx.x;              // 0..3071, LPT: heavy q-tiles first
    const int qt  = 63 - (bx / 48);
    const int rem = bx % 48;
    const int h   = rem % 12;
    const int c   = rem / 12;                // chunk 0..3 (16 k-tiles each)
    const int group = h >> 2;
    const int sl    = 1024 << group;
    const int causal = (*is_causal_p) != 0;

    const int q0 = qt << 6;
    const int qb = q0 & (sl - 1);
    const int seg_start = q0 - qb;
    const int diag_kt = qb >> 6;
    const int nkt = causal ? (diag_kt + 1) : (sl >> 6);
    const int kt0 = c << 4;
    if (kt0 >= nkt) return;
    const int kend = min(kt0 + 16, nkt);
    const int nch  = (nkt + 15) >> 4;

    const int tid  = threadIdx.x;
    const int wave = tid >> 6;
    const int lane = tid & 63;
    const int l15  = lane & 15;
    const int quad = lane >> 4;

    __shared__ __align__(16) __bf16 Ks[2][64 * LDK];   // [key][d]
    __shared__ __align__(16) __bf16 Vs[2][64 * LDK];   // [d][s] (key-permuted)

    const int srow = tid >> 3;               // 0..31
    const int scol = (tid & 7) << 3;         // 0..56
    const ushort_t* kg_head = Kg + (size_t)h * 4096 * 64;
    const ushort_t* vq_head = Vq + (size_t)h * 64 * 4096;

    // ---- Q B-frags (B[k=d][n=q]: n=l15, k=quad*8+j), scale = 0.125*log2(e) ----
    bf16x8 bq0, bq1;
    {
        const float s = 0.125f * 1.4426950408889634f;
        const int qrow = q0 + wave * 16 + l15;
        const float* qptr = Q + (size_t)qrow * HD + h * 64;
        float4 x0 = ((const float4*)(qptr + quad * 8))[0];
        float4 x1 = ((const float4*)(qptr + quad * 8))[1];
        float4 y0 = ((const float4*)(qptr + 32 + quad * 8))[0];
        float4 y1 = ((const float4*)(qptr + 32 + quad * 8))[1];
        bq0[0]=(__bf16)(x0.x*s); bq0[1]=(__bf16)(x0.y*s); bq0[2]=(__bf16)(x0.z*s); bq0[3]=(__bf16)(x0.w*s);
        bq0[4]=(__bf16)(x1.x*s); bq0[5]=(__bf16)(x1.y*s); bq0[6]=(__bf16)(x1.z*s); bq0[7]=(__bf16)(x1.w*s);
        bq1[0]=(__bf16)(y0.x*s); bq1[1]=(__bf16)(y0.y*s); bq1[2]=(__bf16)(y0.z*s); bq1[3]=(__bf16)(y0.w*s);
        bq1[4]=(__bf16)(y1.x*s); bq1[5]=(__bf16)(y1.y*s); bq1[6]=(__bf16)(y1.z*s); bq1[7]=(__bf16)(y1.w*s);
    }

    f32x4 o[4];
    #pragma unroll
    for (int t = 0; t < 4; ++t) o[t] = (f32x4){0.f, 0.f, 0.f, 0.f};
    float l_r = 0.f;
    const int q_in_seg = qb + wave * 16 + l15;

    // 1-deep prefetch with SCALAR-named registers (no arrays -> no scratch demotion)
    bf16x8 kr0, kr1, vr0, vr1;
    auto load_tile = [&](int kt) {
        const ushort_t* kb = kg_head + (size_t)(seg_start + (kt << 6)) * 64;
        kr0 = *(const bf16x8*)(kb + srow * 64 + scol);
        kr1 = *(const bf16x8*)(kb + (srow + 32) * 64 + scol);
        const ushort_t* vb = vq_head + (size_t)((seg_start >> 6) + kt) * 4096;
        vr0 = *(const bf16x8*)(vb + srow * 64 + scol);
        vr1 = *(const bf16x8*)(vb + (srow + 32) * 64 + scol);
    };
    auto store_tile = [&](int buf) {
        *(bf16x8*)&Ks[buf][srow * LDK + scol]        = kr0;
        *(bf16x8*)&Ks[buf][(srow + 32) * LDK + scol] = kr1;
        *(bf16x8*)&Vs[buf][srow * LDK + scol]        = vr0;
        *(bf16x8*)&Vs[buf][(srow + 32) * LDK + scol] = vr1;
    };

    load_tile(kt0);
    store_tile(0);
    __syncthreads();

    for (int kt = kt0; kt < kend; ++kt) {
        const int cur = (kt - kt0) & 1;
        const bool more = (kt + 1 < kend);
        if (more) load_tile(kt + 1);   // prefetch overlaps compute below

        // ---- S^T = K * Q^T : A = K-frag from LDS (m=key), B = Q-frag ----
        f32x4 sacc[4];
        #pragma unroll
        for (int kg = 0; kg < 4; ++kg) {
            bf16x8 ka0 = *(const bf16x8*)&Ks[cur][(kg * 16 + l15) * LDK + quad * 8];
            bf16x8 ka1 = *(const bf16x8*)&Ks[cur][(kg * 16 + l15) * LDK + 32 + quad * 8];
            f32x4 cc = (f32x4){0.f, 0.f, 0.f, 0.f};
            cc = __builtin_amdgcn_mfma_f32_16x16x32_bf16(ka0, bq0, cc, 0, 0, 0);
            cc = __builtin_amdgcn_mfma_f32_16x16x32_bf16(ka1, bq1, cc, 0, 0, 0);
            sacc[kg] = cc;
        }

        // ---- P^T = 2^(S^T) in registers; pack straight into PV B-frags ----
        const bool maskT = causal && (kt == diag_kt);
        bf16x8 pb[2];
        #pragma unroll
        for (int kg = 0; kg < 4; ++kg) {
            #pragma unroll
            for (int r = 0; r < 4; ++r) {
                const int key = (kt << 6) + kg * 16 + quad * 4 + r;
                float p = __builtin_amdgcn_exp2f(sacc[kg][r]);
                if (maskT && key > q_in_seg) p = 0.f;
                l_r += p;
                pb[kg >> 1][(kg & 1) * 4 + r] = (__bf16)p;
            }
        }

        // ---- O^T += V^T * P^T : A = permuted V-frag from LDS (b128), B = pb ----
        #pragma unroll
        for (int kp2 = 0; kp2 < 2; ++kp2) {
            #pragma unroll
            for (int t = 0; t < 4; ++t) {
                bf16x8 va = *(const bf16x8*)&Vs[cur][(t * 16 + l15) * LDK + kp2 * 32 + quad * 8];
                o[t] = __builtin_amdgcn_mfma_f32_16x16x32_bf16(va, pb[kp2], o[t], 0, 0, 0);
            }
        }

        if (more) store_tile(cur ^ 1);
        __syncthreads();
    }

    // ---- epilogue: l held per (q=l15, quad) -> reduce across quads only ----
    l_r += __shfl_xor(l_r, 16, 64);
    l_r += __shfl_xor(l_r, 32, 64);
    const int row = q0 + wave * 16 + l15;
    if (nch == 1) {
        const float inv = 1.0f / l_r;
        #pragma unroll
        for (int t = 0; t < 4; ++t) {
            f32x4 v = o[t];
            float4 w = {v[0] * inv, v[1] * inv, v[2] * inv, v[3] * inv};
            *(float4*)(Out + (size_t)row * HD + h * 64 + t * 16 + quad * 4) = w;
        }
    } else {
        if (lane < 16) atomicAdd(&l_acc[row * 12 + h], l_r);
        #pragma unroll
        for (int t = 0; t < 4; ++t)
            #pragma unroll
            for (int r = 0; r < 4; ++r)
                atomicAdd(&Out[(size_t)row * HD + h * 64 + t * 16 + quad * 4 + r], o[t][r]);
    }
}

// ---- finalize: divide multi-chunk rows (nkt > 16) by accumulated l ----
__global__ __launch_bounds__(256)
void finalize_kernel(float* __restrict__ Out, const float* __restrict__ l_acc,
                     const int* __restrict__ is_causal_p)
{
    const int causal = (*is_causal_p) != 0;
    const int idx = blockIdx.x * 256 + threadIdx.x;
    const int rh = idx >> 4;
    const int d4 = idx & 15;
    const int h = rh % 12;
    const int row = rh / 12;
    const int group = h >> 2;
    const int sl = 1024 << group;
    const int q0 = row & ~63;
    const int qb = q0 & (sl - 1);
    const int nkt = causal ? ((qb >> 6) + 1) : (sl >> 6);
    if (nkt <= 16) return;
    const float inv = 1.0f / l_acc[rh];
    float4* p = (float4*)Out + (size_t)rh * 16 + d4;
    float4 v = *p;
    v.x *= inv; v.y *= inv; v.z *= inv; v.w *= inv;
    *p = v;
}

extern "C" void kernel_launch(void* const* d_in, const int* in_sizes, int n_in,
                              void* d_out, int out_size, void* d_ws, size_t ws_size,
                              hipStream_t stream) {
    (void)in_sizes; (void)n_in; (void)out_size; (void)ws_size;
    const float* Q = (const float*)d_in[0];
    const float* K = (const float*)d_in[1];
    const float* V = (const float*)d_in[2];
    const int* isc = (const int*)d_in[3];
    float* Out = (float*)d_out;
    ushort_t* Kg   = (ushort_t*)((char*)d_ws + KG_OFF);
    ushort_t* Vq   = (ushort_t*)((char*)d_ws + VQ_OFF);
    float*    lacc = (float*)((char*)d_ws + LACC_OFF);

    hipMemsetAsync(Out, 0, (size_t)4096 * 12 * 64 * 4, stream);
    hipMemsetAsync(lacc, 0, (size_t)4096 * 12 * 4, stream);
    preconvert_kernel<<<1536, 256, 0, stream>>>(K, V, Kg, Vq);
    dilated_attn_kernel<<<3072, 256, 0, stream>>>(Q, Kg, Vq, isc, Out, lacc);
    finalize_kernel<<<3072, 256, 0, stream>>>(Out, lacc, isc);
}